// Round 1
// baseline (106.007 us; speedup 1.0000x reference)
//
#include <hip/hip_runtime.h>

#define HH 512
#define WW 512
#define NB 4            // batch
#define NC 3            // channels
#define NK 33           // histogram grid points
#define SPC 0.0625f     // 2/32

// workspace layout, in 4-byte words:
//   [0 .. 31]        int   bbox[2][NB][4]   {ymin, ymax, xmin, xmax} raw (unpadded)
//   [32 .. 2407]     float num[2][NB][3][NC][NK]
//   [2408 .. 2431]   int   cnt[2][NB][3]
#define BBOX_OFF 0
#define NUM_OFF  32
#define CNT_OFF  (32 + 2*NB*3*NC*NK)   // 2408
#define WS_TOTAL (CNT_OFF + 2*NB*3)    // 2432

__global__ void k_init(int* wsi, float* wsf) {
    for (int i = threadIdx.x; i < WS_TOTAL; i += blockDim.x) {
        if (i < NUM_OFF) {
            int v = i & 3;  // 0:ymin 1:ymax 2:xmin 3:xmax
            wsi[i] = (v == 0) ? HH : (v == 1) ? -1 : (v == 2) ? WW : -1;
        } else if (i < CNT_OFF) {
            wsf[i] = 0.0f;
        } else {
            wsi[i] = 0;
        }
    }
}

#define BBOX_CH 16
__global__ void k_bbox(const int* __restrict__ seg_gen,
                       const int* __restrict__ seg_real,
                       int* wsi) {
    int bid = blockIdx.x;
    int map = bid / (NB * BBOX_CH);
    int rem = bid % (NB * BBOX_CH);
    int b = rem / BBOX_CH;
    int chunk = rem % BBOX_CH;
    const int* seg = (map == 0 ? seg_gen : seg_real) + b * HH * WW;
    const int PIX = HH * WW / BBOX_CH;       // 16384
    int base = chunk * PIX;
    int tid = (int)threadIdx.x;

    int ymin = HH, ymax = -1, xmin = WW, xmax = -1;
    for (int it = 0; it < PIX / 256; ++it) {
        int p = base + it * 256 + tid;
        int s = seg[p];
        if (s == 4 || s == 5) {
            int h = p >> 9, w = p & (WW - 1);
            ymin = min(ymin, h); ymax = max(ymax, h);
            xmin = min(xmin, w); xmax = max(xmax, w);
        }
    }
    __shared__ int sy0[256], sy1[256], sx0[256], sx1[256];
    sy0[tid] = ymin; sy1[tid] = ymax; sx0[tid] = xmin; sx1[tid] = xmax;
    __syncthreads();
    for (int off = 128; off > 0; off >>= 1) {
        if (tid < off) {
            sy0[tid] = min(sy0[tid], sy0[tid + off]);
            sy1[tid] = max(sy1[tid], sy1[tid + off]);
            sx0[tid] = min(sx0[tid], sx0[tid + off]);
            sx1[tid] = max(sx1[tid], sx1[tid + off]);
        }
        __syncthreads();
    }
    if (tid == 0) {
        int* bb = wsi + BBOX_OFF + (map * NB + b) * 4;
        atomicMin(&bb[0], sy0[0]);
        atomicMax(&bb[1], sy1[0]);
        atomicMin(&bb[2], sx0[0]);
        atomicMax(&bb[3], sx1[0]);
    }
}

#define HIST_CH 64
__global__ void k_hist(const float* __restrict__ gen,
                       const float* __restrict__ realv,
                       const int* __restrict__ seg_gen,
                       const int* __restrict__ seg_real,
                       int* wsi, float* wsf) {
    int bid = blockIdx.x;
    int map = bid / (NB * HIST_CH);
    int rem = bid % (NB * HIST_CH);
    int b = rem / HIST_CH;
    int chunk = rem % HIST_CH;
    const float* img = (map == 0 ? gen : realv);
    const int* seg = (map == 0 ? seg_gen : seg_real) + b * HH * WW;
    int tid = (int)threadIdx.x;

    __shared__ float hist[3 * NC * NK];   // [r][c][k], 297 floats
    __shared__ int scnt[3];
    for (int i = tid; i < 3 * NC * NK; i += 256) hist[i] = 0.0f;
    if (tid < 3) scnt[tid] = 0;

    // padded eye bbox (replicates reference, incl. the double-pad quirk)
    const int* bb = wsi + BBOX_OFF + (map * NB + b) * 4;
    int ymin0 = bb[0], ymax0 = bb[1], xmin0 = bb[2], xmax0 = bb[3];
    bool has = (ymax0 >= 0);
    int pady = (int)(0.15f * (float)(ymax0 - ymin0));
    int padx = (int)(0.15f * (float)(xmax0 - xmin0));
    int ymin = max(0, ymin0 - pady);
    int ymax = min(HH, ymax0 + pady);
    int xmin = max(0, xmin0 - padx);
    int xmax = min(WW, xmax0 + padx);
    ymax = min(HH - 1, ymax + pady);
    xmax = min(WW - 1, xmax + padx);
    __syncthreads();

    const int PIX = HH * WW / HIST_CH;    // 4096
    int base = chunk * PIX;
    int cl = 0, cf = 0, ce = 0;
    for (int it = 0; it < PIX / 256; ++it) {
        int p = base + it * 256 + tid;
        int s = seg[p];
        int h = p >> 9, w = p & (WW - 1);
        bool lips = (s == 11) | (s == 12);
        bool face = (s == 1);
        bool eye = has & (h >= ymin) & (h < ymax) & (w >= xmin) & (w < xmax);
        cl += lips; cf += face; ce += eye;
        if (!(lips | face | eye)) continue;
        #pragma unroll
        for (int c = 0; c < NC; ++c) {
            float x = img[((b * NC + c) << 18) + p];
            float t = (x + 1.0f) * 16.0f;
            int k0 = (int)floorf(t);
            k0 = min(max(k0, 0), NK - 1);
            float g0 = -1.0f + SPC * (float)k0;
            float c0 = fmaxf(SPC - fabsf(x - g0), 0.0f);
            float c1 = fmaxf(SPC - fabsf(x - (g0 + SPC)), 0.0f);
            bool two = (k0 < NK - 1);
            if (lips) {
                atomicAdd(&hist[0 * NC * NK + c * NK + k0], c0);
                if (two) atomicAdd(&hist[0 * NC * NK + c * NK + k0 + 1], c1);
            }
            if (face) {
                atomicAdd(&hist[1 * NC * NK + c * NK + k0], c0);
                if (two) atomicAdd(&hist[1 * NC * NK + c * NK + k0 + 1], c1);
            }
            if (eye) {
                atomicAdd(&hist[2 * NC * NK + c * NK + k0], c0);
                if (two) atomicAdd(&hist[2 * NC * NK + c * NK + k0 + 1], c1);
            }
        }
    }
    if (cl) atomicAdd(&scnt[0], cl);
    if (cf) atomicAdd(&scnt[1], cf);
    if (ce) atomicAdd(&scnt[2], ce);
    __syncthreads();

    float* gnum = wsf + NUM_OFF + (map * NB + b) * (3 * NC * NK);
    for (int i = tid; i < 3 * NC * NK; i += 256) {
        float v = hist[i];
        if (v != 0.0f) atomicAdd(&gnum[i], v);
    }
    int* gcnt = wsi + CNT_OFF + (map * NB + b) * 3;
    if (tid < 3 && scnt[tid]) atomicAdd(&gcnt[tid], scnt[tid]);
}

__global__ void k_final(const float* wsf, const int* wsi, float* out) {
    int tid = (int)threadIdx.x;   // 64 threads
    double part = 0.0;
    if (tid < NB * 3 * NC) {      // 36 items: (b, r, c)
        int b = tid / (3 * NC);
        int r = (tid / NC) % 3;
        int c = tid % NC;
        int ig = (0 * NB + b) * 3 + r;
        int ir = (1 * NB + b) * 3 + r;
        int ng = wsi[CNT_OFF + ig];
        int nr = wsi[CNT_OFF + ir];
        if (ng > 0 && nr > 0) {
            const float* numg = wsf + NUM_OFF + ig * (NC * NK) + c * NK;
            const float* numr = wsf + NUM_OFF + ir * (NC * NK) + c * NK;
            float Sg = 0.0f, Sr = 0.0f;
            for (int k = 0; k < NK; ++k) { Sg += numg[k]; Sr += numr[k]; }
            float dg = (float)ng * Sg;
            float dr = (float)nr * Sr;
            dg = (dg > 0.0f) ? dg : 1.0f;
            dr = (dr > 0.0f) ? dr : 1.0f;
            double acc = 0.0;
            for (int k = 0; k < NK; ++k) {
                float hg = numg[k] / dg;
                float hr = numr[k] / dr;
                acc += fabs((double)hg - (double)hr);
            }
            double wgt = (r == 1) ? 0.1 : 1.0;
            part = wgt * acc / (double)NK;
        }
    }
    __shared__ double sred[64];
    sred[tid] = part;
    __syncthreads();
    for (int off = 32; off > 0; off >>= 1) {
        if (tid < off) sred[tid] += sred[tid + off];
        __syncthreads();
    }
    if (tid == 0) out[0] = (float)(sred[0] / (double)(NB * NC * 3));
}

extern "C" void kernel_launch(void* const* d_in, const int* in_sizes, int n_in,
                              void* d_out, int out_size, void* d_ws, size_t ws_size,
                              hipStream_t stream) {
    const float* gen    = (const float*)d_in[0];
    const float* realv  = (const float*)d_in[1];
    const int* seg_gen  = (const int*)d_in[2];
    const int* seg_real = (const int*)d_in[3];
    int*   wsi = (int*)d_ws;
    float* wsf = (float*)d_ws;

    k_init <<<dim3(1),                    dim3(256), 0, stream>>>(wsi, wsf);
    k_bbox <<<dim3(2 * NB * BBOX_CH),     dim3(256), 0, stream>>>(seg_gen, seg_real, wsi);
    k_hist <<<dim3(2 * NB * HIST_CH),     dim3(256), 0, stream>>>(gen, realv, seg_gen, seg_real, wsi, wsf);
    k_final<<<dim3(1),                    dim3(64),  0, stream>>>(wsf, wsi, (float*)d_out);
}